// Round 8
// baseline (11513.800 us; speedup 1.0000x reference)
//
#include <hip/hip_runtime.h>
#include <hip/hip_fp16.h>
#include <math.h>

#define THREADS 256

static inline int ceil_div(int a, int b) { return (a + b - 1) / b; }

__device__ __forceinline__ float wave_sum_all(float v) {
#pragma unroll
  for (int m = 1; m < 64; m <<= 1) v += __shfl_xor(v, m);
  return v;
}
__device__ __forceinline__ float wave_max_all(float v) {
#pragma unroll
  for (int m = 1; m < 64; m <<= 1) v = fmaxf(v, __shfl_xor(v, m));
  return v;
}

// fp16 gather, 8 features per lane via 16B loads, 4 edges in flight.
// acc[8] f32 accumulators. Transactions per edge = D/8 (4x fewer than half2).
template <int D>
__device__ __forceinline__ void gather_row8h(const int* __restrict__ crow,
                                             const float* __restrict__ cval,
                                             const __half* __restrict__ Z, int e0, int e1,
                                             int jj8, float* __restrict__ acc) {
#pragma unroll
  for (int k = 0; k < 8; ++k) acc[k] = 0.f;
  for (int e = e0; e < e1; e += 4) {
    int r[4];
    float v[4];
#pragma unroll
    for (int u = 0; u < 4; ++u) {
      int ee = e + u;
      bool ok = ee < e1;
      r[u] = ok ? crow[ee] : 0;
      v[u] = ok ? cval[ee] : 0.f;
    }
    float4 z[4];
#pragma unroll
    for (int u = 0; u < 4; ++u) z[u] = *(const float4*)&Z[(size_t)r[u] * D + jj8];
#pragma unroll
    for (int u = 0; u < 4; ++u) {
      const __half2* h = (const __half2*)&z[u];
      float2 f0 = __half22float2(h[0]);
      float2 f1 = __half22float2(h[1]);
      float2 f2 = __half22float2(h[2]);
      float2 f3 = __half22float2(h[3]);
      acc[0] += v[u] * f0.x;
      acc[1] += v[u] * f0.y;
      acc[2] += v[u] * f1.x;
      acc[3] += v[u] * f1.y;
      acc[4] += v[u] * f2.x;
      acc[5] += v[u] * f2.y;
      acc[6] += v[u] * f3.x;
      acc[7] += v[u] * f3.y;
    }
  }
}

// f32 gather, 4 features per lane via 16B loads, 4 edges in flight (spmm_bt).
template <int D>
__device__ __forceinline__ void gather_row4f(const int* __restrict__ crow,
                                             const float* __restrict__ cval,
                                             const float* __restrict__ Z, int e0, int e1,
                                             int jj4, float* __restrict__ acc) {
#pragma unroll
  for (int k = 0; k < 4; ++k) acc[k] = 0.f;
  for (int e = e0; e < e1; e += 4) {
    int r[4];
    float v[4];
#pragma unroll
    for (int u = 0; u < 4; ++u) {
      int ee = e + u;
      bool ok = ee < e1;
      r[u] = ok ? crow[ee] : 0;
      v[u] = ok ? cval[ee] : 0.f;
    }
    float4 z[4];
#pragma unroll
    for (int u = 0; u < 4; ++u) z[u] = *(const float4*)&Z[(size_t)r[u] * D + jj4];
#pragma unroll
    for (int u = 0; u < 4; ++u) {
      acc[0] += v[u] * z[u].x;
      acc[1] += v[u] * z[u].y;
      acc[2] += v[u] * z[u].z;
      acc[3] += v[u] * z[u].w;
    }
  }
}

// ---------------- build helpers ----------------

__global__ __launch_bounds__(THREADS) void zero_i32(int* p, int n) {
  int i = blockIdx.x * THREADS + threadIdx.x;
  if (i < n) p[i] = 0;
}

__global__ __launch_bounds__(THREADS) void init_power(float* v, float* norm2, int n, float c) {
  int i = blockIdx.x * THREADS + threadIdx.x;
  if (i < n) v[i] = c;
  if (blockIdx.x == 0 && threadIdx.x < 64) norm2[threadIdx.x] = 0.f;
}

__global__ __launch_bounds__(THREADS) void hist_deg(const int* __restrict__ row,
                                                    const int* __restrict__ col,
                                                    int* rdeg, int* cdeg, int E) {
  int e = blockIdx.x * THREADS + threadIdx.x;
  if (e < E) {
    atomicAdd(&rdeg[row[e]], 1);
    atomicAdd(&cdeg[col[e]], 1);
  }
}

__global__ __launch_bounds__(THREADS) void scan1(const int* __restrict__ in, int* bsum, int L) {
  __shared__ int lds[THREADS];
  int idx = blockIdx.x * THREADS + threadIdx.x;
  lds[threadIdx.x] = (idx < L) ? in[idx] : 0;
  __syncthreads();
  for (int off = THREADS / 2; off > 0; off >>= 1) {
    if (threadIdx.x < off) lds[threadIdx.x] += lds[threadIdx.x + off];
    __syncthreads();
  }
  if (threadIdx.x == 0) bsum[blockIdx.x] = lds[0];
}

__global__ __launch_bounds__(THREADS) void scan2(int* bsum, int B) {
  __shared__ int lds[THREADS];
  int t = threadIdx.x;
  lds[t] = (t < B) ? bsum[t] : 0;
  __syncthreads();
  for (int off = 1; off < THREADS; off <<= 1) {
    int add = (t >= off) ? lds[t - off] : 0;
    __syncthreads();
    lds[t] += add;
    __syncthreads();
  }
  if (t < B) bsum[t] = (t == 0) ? 0 : lds[t - 1];
}

__global__ __launch_bounds__(THREADS) void scan3(int* data, const int* __restrict__ bsum, int L) {
  __shared__ int lds[THREADS];
  int t = threadIdx.x;
  int idx = blockIdx.x * THREADS + t;
  int v = (idx < L) ? data[idx] : 0;
  lds[t] = v;
  __syncthreads();
  for (int off = 1; off < THREADS; off <<= 1) {
    int add = (t >= off) ? lds[t - off] : 0;
    __syncthreads();
    lds[t] += add;
    __syncthreads();
  }
  if (idx < L) data[idx] = lds[t] - v + bsum[blockIdx.x];
}

__global__ __launch_bounds__(THREADS) void scatter_edges(
    const int* __restrict__ row, const int* __restrict__ col, const float* __restrict__ val,
    const int* __restrict__ rstart, int* rcur, int* csr_col, float* csr_val,
    const int* __restrict__ cstart, int* ccur, int* csc_row, float* csc_val, int E) {
  int e = blockIdx.x * THREADS + threadIdx.x;
  if (e < E) {
    int r = row[e], c = col[e];
    float v = val[e];
    int p = rstart[r] + atomicAdd(&rcur[r], 1);
    csr_col[p] = c;
    csr_val[p] = v;
    int q = cstart[c] + atomicAdd(&ccur[c], 1);
    csc_row[q] = r;
    csc_val[q] = v;
  }
}

// ---------------- power iteration (UNNORMALIZED chain) ----------------
__global__ __launch_bounds__(THREADS) void power_spmv_nn(
    const int* __restrict__ rs, const int* __restrict__ rcol, const float* __restrict__ rval,
    const float* __restrict__ vin, float* __restrict__ vout, int n) {
  int gid = blockIdx.x * THREADS + threadIdx.x;
  int node = gid >> 2;
  int sl = gid & 3;
  if (node >= n) return;
  int e0 = rs[node], e1 = rs[node + 1];
  float a0 = 0.f, a1 = 0.f, a2 = 0.f, a3 = 0.f;
  for (int e = e0 + sl; e < e1; e += 16) {
    int ee1 = e + 4, ee2 = e + 8, ee3 = e + 12;
    bool k1 = ee1 < e1, k2 = ee2 < e1, k3 = ee3 < e1;
    int r0 = rcol[e];
    int r1 = k1 ? rcol[ee1] : 0;
    int r2 = k2 ? rcol[ee2] : 0;
    int r3 = k3 ? rcol[ee3] : 0;
    float v0 = rval[e];
    float v1 = k1 ? rval[ee1] : 0.f;
    float v2 = k2 ? rval[ee2] : 0.f;
    float v3 = k3 ? rval[ee3] : 0.f;
    a0 += v0 * vin[r0];
    a1 += v1 * vin[r1];
    a2 += v2 * vin[r2];
    a3 += v3 * vin[r3];
  }
  float w = (a0 + a1) + (a2 + a3);
  w += __shfl_xor(w, 1);
  w += __shfl_xor(w, 2);
  if (sl == 0) vout[node] = w;
}

// n2[0] += ||u||^2 ; n2[1] += ||w||^2
__global__ __launch_bounds__(THREADS) void norm2_pair(const float* __restrict__ u,
                                                      const float* __restrict__ w,
                                                      float* norm2, int n) {
  int i = blockIdx.x * THREADS + threadIdx.x;
  float a = (i < n) ? u[i] : 0.f;
  float b = (i < n) ? w[i] : 0.f;
  float sa = wave_sum_all(a * a);
  float sb = wave_sum_all(b * b);
  __shared__ float pa[4], pb[4];
  if ((threadIdx.x & 63) == 0) {
    pa[threadIdx.x >> 6] = sa;
    pb[threadIdx.x >> 6] = sb;
  }
  __syncthreads();
  if (threadIdx.x == 0) atomicAdd(&norm2[0], pa[0] + pa[1] + pa[2] + pa[3]);
  if (threadIdx.x == 64) atomicAdd(&norm2[1], pb[0] + pb[1] + pb[2] + pb[3]);
}

// ---------------- transposes ----------------

__global__ __launch_bounds__(256) void transpose_feat(const float* __restrict__ in,
                                                      float* __restrict__ out, int n) {
  __shared__ float tile[32][33];
  int bx = blockIdx.x;
  int by = blockIdx.y;
  int x = bx * 32 + threadIdx.x;
  for (int dy = threadIdx.y; dy < 32; dy += 8) {
    int y = by * 32 + dy;
    tile[dy][threadIdx.x] = (x < n) ? in[(size_t)y * n + x] : 0.f;
  }
  __syncthreads();
  for (int dy = threadIdx.y; dy < 32; dy += 8) {
    int node = bx * 32 + dy;
    int feat = by * 32 + threadIdx.x;
    if (node < n) out[(size_t)node * 128 + feat] = tile[threadIdx.x][dy];
  }
}

__global__ __launch_bounds__(THREADS) void transpose_small(const float* __restrict__ in,
                                                           float* __restrict__ out, int rows,
                                                           int cols) {
  int idx = blockIdx.x * THREADS + threadIdx.x;
  if (idx < rows * cols) {
    int r = idx / cols, c = idx % cols;
    out[c * rows + r] = in[idx];
  }
}

// ---------------- projection (row-wise L1 projection via bisection) ----------------
template <int D>
__global__ __launch_bounds__(64) void project_row(const float* __restrict__ W,
                                                  float* __restrict__ WpT,
                                                  const float* __restrict__ norm2) {
  int o = blockIdx.x;
  int l = threadIdx.x;
  float rho = sqrtf(norm2[0] / norm2[1]) + 1e-12f;
  float k = 0.9f / rho;
  float a0 = (l < D) ? W[o * D + l] : 0.f;
  float a1 = (64 + l < D) ? W[o * D + 64 + l] : 0.f;
  float ab0 = fabsf(a0), ab1 = fabsf(a1);
  float s = wave_sum_all(ab0 + ab1);
  float mx = wave_max_all(fmaxf(ab0, ab1));
  float w0 = a0, w1 = a1;
  if (s > k) {
    float lo = 0.f, hi = mx;
    for (int it = 0; it < 50; ++it) {
      float mid = 0.5f * (lo + hi);
      float g = wave_sum_all(fmaxf(ab0 - mid, 0.f) + fmaxf(ab1 - mid, 0.f));
      if (g > k) lo = mid; else hi = mid;
    }
    float theta = 0.5f * (lo + hi);
    w0 = copysignf(fmaxf(ab0 - theta, 0.f), a0);
    w1 = copysignf(fmaxf(ab1 - theta, 0.f), a1);
  }
  if (l < D) WpT[l * D + o] = w0;
  if (64 + l < D) WpT[(64 + l) * D + o] = w1;
}

// ---------------- spmm for bt (fp16) + Zinit = relu(bt) (fp16) ----------------
// 4 features per lane via float4 loads; transactions per edge = DOUT/4.
template <int DOUT>
__global__ __launch_bounds__(THREADS, 8) void spmm_bt(
    const int* __restrict__ cstart, const int* __restrict__ crow, const float* __restrict__ cval,
    const float* __restrict__ X, __half* __restrict__ bt, __half* __restrict__ Zinit, int n) {
  constexpr int QD = DOUT / 4;
  int idx = blockIdx.x * THREADS + threadIdx.x;
  int node = idx / QD;
  int jj4 = (idx % QD) * 4;
  if (node >= n) return;
  int e0 = cstart[node], e1 = cstart[node + 1];
  float acc[4];
  gather_row4f<DOUT>(crow, cval, X, e0, e1, jj4, acc);
  size_t o = (size_t)node * DOUT + jj4;
  *(__half2*)&bt[o] = __floats2half2_rn(acc[0], acc[1]);
  *(__half2*)&bt[o + 2] = __floats2half2_rn(acc[2], acc[3]);
  *(__half2*)&Zinit[o] = __floats2half2_rn(fmaxf(acc[0], 0.f), fmaxf(acc[1], 0.f));
  *(__half2*)&Zinit[o + 2] = __floats2half2_rn(fmaxf(acc[2], 0.f), fmaxf(acc[3], 0.f));
}

// ---------------- fused fixed-point step: Zout = relu( (A^T Zin) @ WpT + bt ) ------
// Zin/Zout/bt fp16; WpT, LDS tile, accumulation f32. One node per thread in
// phase 1, 8 features per 16B load, 4 edges in flight.
template <int DOUT, int NB>
__global__ __launch_bounds__(THREADS, 8) void fp_step(
    const int* __restrict__ cstart, const int* __restrict__ crow, const float* __restrict__ cval,
    const __half* __restrict__ Zin, const float* __restrict__ WpT, const __half* __restrict__ bt,
    __half* __restrict__ Zout, int n) {
  constexpr int TO = DOUT / 4;
  constexpr int TN = THREADS / TO;
  constexpr int NT = NB / TN;
  constexpr int TPN = DOUT / 8;             // threads per node in phase 1
  constexpr int LG = THREADS / TPN;         // nodes gathered in parallel
  static_assert(NB == LG, "one node per thread");
  __shared__ float sT[NB][DOUT + 4];
  const int node0 = blockIdx.x * NB;
  const int tid = threadIdx.x;
  // phase 1: gather S rows into LDS
  {
    const int jj8 = (tid % TPN) * 8;
    const int nn = tid / TPN;
    const int node = node0 + nn;
    float acc[8];
#pragma unroll
    for (int k = 0; k < 8; ++k) acc[k] = 0.f;
    if (node < n) {
      int e0 = cstart[node], e1 = cstart[node + 1];
      gather_row8h<DOUT>(crow, cval, Zin, e0, e1, jj8, acc);
    }
    *(float4*)&sT[nn][jj8] = make_float4(acc[0], acc[1], acc[2], acc[3]);
    *(float4*)&sT[nn][jj8 + 4] = make_float4(acc[4], acc[5], acc[6], acc[7]);
  }
  __syncthreads();
  // phase 2: register-tiled GEMM  C[n][o] = sum_j S[n][j] * WpT[j][o]
  const int o4 = tid % TO, tg = tid / TO;
  const int o0 = o4 * 4;
  float acc[NT][4];
#pragma unroll
  for (int a = 0; a < NT; ++a) acc[a][0] = acc[a][1] = acc[a][2] = acc[a][3] = 0.f;
  for (int jz = 0; jz < DOUT; ++jz) {
    const float4 w4 = *(const float4*)&WpT[jz * DOUT + o0];
#pragma unroll
    for (int a = 0; a < NT; ++a) {
      float sv = sT[tg * NT + a][jz];
      acc[a][0] += sv * w4.x;
      acc[a][1] += sv * w4.y;
      acc[a][2] += sv * w4.z;
      acc[a][3] += sv * w4.w;
    }
  }
#pragma unroll
  for (int a = 0; a < NT; ++a) {
    int node = node0 + tg * NT + a;
    if (node < n) {
      size_t o = (size_t)node * DOUT + o0;
      float2 b01 = __half22float2(*(const __half2*)&bt[o]);
      float2 b23 = __half22float2(*(const __half2*)&bt[o + 2]);
      float zx = fmaxf(acc[a][0] + b01.x, 0.f);
      float zy = fmaxf(acc[a][1] + b01.y, 0.f);
      float zz = fmaxf(acc[a][2] + b23.x, 0.f);
      float zw = fmaxf(acc[a][3] + b23.y, 0.f);
      *(__half2*)&Zout[o] = __floats2half2_rn(zx, zy);
      *(__half2*)&Zout[o + 2] = __floats2half2_rn(zz, zw);
    }
  }
}

// ---------------- dense GEMM: Out = act( X @ MT + bias + Addh ) ----------------
template <int DOUT, int NB>
__global__ __launch_bounds__(THREADS) void dense_gemm(
    const float* __restrict__ X, int din, const float* __restrict__ MT,
    const float* __restrict__ bias, const __half* __restrict__ Addh, int act,
    float* __restrict__ Out, int n) {
  constexpr int TO = DOUT / 4;
  constexpr int TN = THREADS / TO;
  constexpr int NT = NB / TN;
  __shared__ float xs[NB][129];
  const int node0 = blockIdx.x * NB;
  const int tid = threadIdx.x;
  for (int idx = tid; idx < NB * din; idx += THREADS) {
    int nn = idx / din, j = idx % din;
    int node = node0 + nn;
    xs[nn][j] = (node < n) ? X[(size_t)node * din + j] : 0.f;
  }
  __syncthreads();
  const int o4 = tid % TO, tg = tid / TO;
  const int o0 = o4 * 4;
  float acc[NT][4];
#pragma unroll
  for (int a = 0; a < NT; ++a) acc[a][0] = acc[a][1] = acc[a][2] = acc[a][3] = 0.f;
  for (int j = 0; j < din; ++j) {
    const float4 m4 = *(const float4*)&MT[j * DOUT + o0];
#pragma unroll
    for (int a = 0; a < NT; ++a) {
      float sv = xs[tg * NT + a][j];
      acc[a][0] += sv * m4.x;
      acc[a][1] += sv * m4.y;
      acc[a][2] += sv * m4.z;
      acc[a][3] += sv * m4.w;
    }
  }
#pragma unroll
  for (int a = 0; a < NT; ++a) {
    int node = node0 + tg * NT + a;
    if (node < n) {
      float4 r;
      r.x = acc[a][0]; r.y = acc[a][1]; r.z = acc[a][2]; r.w = acc[a][3];
      if (bias) {
        r.x += bias[o0]; r.y += bias[o0 + 1]; r.z += bias[o0 + 2]; r.w += bias[o0 + 3];
      }
      if (Addh) {
        size_t o = (size_t)node * DOUT + o0;
        float2 a01 = __half22float2(*(const __half2*)&Addh[o]);
        float2 a23 = __half22float2(*(const __half2*)&Addh[o + 2]);
        r.x += a01.x; r.y += a01.y; r.z += a23.x; r.w += a23.y;
      }
      if (act == 1) {
        r.x = (r.x > 0.f) ? r.x : expm1f(r.x);
        r.y = (r.y > 0.f) ? r.y : expm1f(r.y);
        r.z = (r.z > 0.f) ? r.z : expm1f(r.z);
        r.w = (r.w > 0.f) ? r.w : expm1f(r.w);
      }
      *(float4*)&Out[(size_t)node * DOUT + o0] = r;
    }
  }
}

// ---------------- host-side dispatch ----------------

static void launch_project(int dout, const float* W, float* WpT, const float* norm2,
                           hipStream_t s) {
  switch (dout) {
    case 128: project_row<128><<<128, 64, 0, s>>>(W, WpT, norm2); break;
    case 64: project_row<64><<<64, 64, 0, s>>>(W, WpT, norm2); break;
    case 32: project_row<32><<<32, 64, 0, s>>>(W, WpT, norm2); break;
    case 16: project_row<16><<<16, 64, 0, s>>>(W, WpT, norm2); break;
  }
}

static void launch_spmm_bt(int dout, const int* cs, const int* cr, const float* cv,
                           const float* X, __half* bt, __half* Zi, int n, hipStream_t s) {
  int g = ceil_div(n * dout / 4, THREADS);
  switch (dout) {
    case 128: spmm_bt<128><<<g, THREADS, 0, s>>>(cs, cr, cv, X, bt, Zi, n); break;
    case 64: spmm_bt<64><<<g, THREADS, 0, s>>>(cs, cr, cv, X, bt, Zi, n); break;
    case 32: spmm_bt<32><<<g, THREADS, 0, s>>>(cs, cr, cv, X, bt, Zi, n); break;
    case 16: spmm_bt<16><<<g, THREADS, 0, s>>>(cs, cr, cv, X, bt, Zi, n); break;
  }
}

static void launch_fp_step(int dout, const int* cs, const int* cr, const float* cv,
                           const __half* Zin, const float* WpT, const __half* bt, __half* Zout,
                           int n, hipStream_t s) {
  switch (dout) {
    case 128: fp_step<128, 16><<<ceil_div(n, 16), THREADS, 0, s>>>(cs, cr, cv, Zin, WpT, bt, Zout, n); break;
    case 64: fp_step<64, 32><<<ceil_div(n, 32), THREADS, 0, s>>>(cs, cr, cv, Zin, WpT, bt, Zout, n); break;
    case 32: fp_step<32, 64><<<ceil_div(n, 64), THREADS, 0, s>>>(cs, cr, cv, Zin, WpT, bt, Zout, n); break;
    case 16: fp_step<16, 128><<<ceil_div(n, 128), THREADS, 0, s>>>(cs, cr, cv, Zin, WpT, bt, Zout, n); break;
  }
}

static void launch_dense_gemm(int dout, const float* X, int din, const float* MT,
                              const float* bias, const __half* Addh, int act, float* Out, int n,
                              hipStream_t s) {
  switch (dout) {
    case 128: dense_gemm<128, 32><<<ceil_div(n, 32), THREADS, 0, s>>>(X, din, MT, bias, Addh, act, Out, n); break;
    case 64: dense_gemm<64, 32><<<ceil_div(n, 32), THREADS, 0, s>>>(X, din, MT, bias, Addh, act, Out, n); break;
    case 32: dense_gemm<32, 32><<<ceil_div(n, 32), THREADS, 0, s>>>(X, din, MT, bias, Addh, act, Out, n); break;
    case 16: dense_gemm<16, 64><<<ceil_div(n, 64), THREADS, 0, s>>>(X, din, MT, bias, Addh, act, Out, n); break;
  }
}

extern "C" void kernel_launch(void* const* d_in, const int* in_sizes, int n_in, void* d_out,
                              int out_size, void* d_ws, size_t ws_size, hipStream_t stream) {
  const float* features = (const float*)d_in[0];
  const int* row = (const int*)d_in[1];
  const int* col = (const int*)d_in[2];
  const float* val = (const float*)d_in[3];
  const int N = in_sizes[0] / 128;
  const int E = in_sizes[1];
  static const int DIN[5] = {128, 128, 64, 64, 32};
  static const int DOUT[5] = {128, 64, 64, 32, 16};

  char* base = (char*)d_ws;
  size_t off = 0;
  auto alloc = [&](size_t bytes) -> void* {
    off = (off + 255) & ~(size_t)255;
    void* p = (void*)(base + off);
    off += bytes;
    return p;
  };

  int* rstart = (int*)alloc((size_t)(N + 1) * 4);
  int* cstart = (int*)alloc((size_t)(N + 1) * 4);
  int* rcur = (int*)alloc((size_t)N * 4);
  int* ccur = (int*)alloc((size_t)N * 4);
  int* bsum = (int*)alloc(256 * 4);
  float* norm2 = (float*)alloc(64 * 4);
  float* v_a = (float*)alloc((size_t)N * 4);
  float* v_b = (float*)alloc((size_t)N * 4);
  int* csr_col = (int*)alloc((size_t)E * 4);
  float* csr_val = (float*)alloc((size_t)E * 4);
  int* csc_row = (int*)alloc((size_t)E * 4);
  float* csc_val = (float*)alloc((size_t)E * 4);
  float* WpT = (float*)alloc(16384 * 4);
  float* OmT = (float*)alloc(16384 * 4);
  float* PwT = (float*)alloc(16384 * 4);
  float* x0 = (float*)alloc((size_t)N * 128 * 4);
  float* x1 = (float*)alloc((size_t)N * 128 * 4);
  float* xom = (float*)alloc((size_t)N * 128 * 4);
  __half* btb = (__half*)alloc((size_t)N * 128 * 2);
  __half* z_a = (__half*)alloc((size_t)N * 128 * 2);
  __half* z_b = (__half*)alloc((size_t)N * 128 * 2);

  const int gN = ceil_div(N, THREADS);
  const int gE = ceil_div(E, THREADS);
  const int L = N + 1;
  const int B = ceil_div(L, THREADS);

  // ---- build CSR/CSC ----
  zero_i32<<<ceil_div(N + 1, THREADS), THREADS, 0, stream>>>(rstart, N + 1);
  zero_i32<<<ceil_div(N + 1, THREADS), THREADS, 0, stream>>>(cstart, N + 1);
  zero_i32<<<gN, THREADS, 0, stream>>>(rcur, N);
  zero_i32<<<gN, THREADS, 0, stream>>>(ccur, N);
  init_power<<<gN, THREADS, 0, stream>>>(v_a, norm2, N, (float)(1.0 / sqrt((double)N)));
  hist_deg<<<gE, THREADS, 0, stream>>>(row, col, rstart, cstart, E);
  scan1<<<B, THREADS, 0, stream>>>(rstart, bsum, L);
  scan2<<<1, THREADS, 0, stream>>>(bsum, B);
  scan3<<<B, THREADS, 0, stream>>>(rstart, bsum, L);
  scan1<<<B, THREADS, 0, stream>>>(cstart, bsum, L);
  scan2<<<1, THREADS, 0, stream>>>(bsum, B);
  scan3<<<B, THREADS, 0, stream>>>(cstart, bsum, L);
  scatter_edges<<<gE, THREADS, 0, stream>>>(row, col, val, rstart, rcur, csr_col, csr_val,
                                            cstart, ccur, csc_row, csc_val, E);

  // ---- x = features^T ----
  {
    dim3 grid(ceil_div(N, 32), 4);
    dim3 block(32, 8);
    transpose_feat<<<grid, block, 0, stream>>>(features, x0, N);
  }

  // ---- spectral radius: 51 unnormalized SpMVs, then one ratio-norm ----
  {
    int g4 = ceil_div(N * 4, THREADS);
    for (int k = 1; k <= 51; ++k) {
      const float* vin = (k & 1) ? v_a : v_b;
      float* vout = (k & 1) ? v_b : v_a;
      power_spmv_nn<<<g4, THREADS, 0, stream>>>(rstart, csr_col, csr_val, vin, vout, N);
    }
    // v50 ended in v_a, v51 in v_b
    norm2_pair<<<gN, THREADS, 0, stream>>>(v_b, v_a, norm2, N);
  }

  // ---- layers ----
  float* xcur = x0;
  float* xnext = x1;
  for (int i = 0; i < 5; ++i) {
    const int din = DIN[i], dout = DOUT[i];
    const float* W = (const float*)d_in[4 + 4 * i];
    const float* Om = (const float*)d_in[5 + 4 * i];
    const float* Pw = (const float*)d_in[6 + 4 * i];
    const float* Pb = (const float*)d_in[7 + 4 * i];

    transpose_small<<<ceil_div(dout * din, THREADS), THREADS, 0, stream>>>(Om, OmT, dout, din);
    transpose_small<<<ceil_div(dout * din, THREADS), THREADS, 0, stream>>>(Pw, PwT, dout, din);
    launch_project(dout, W, WpT, norm2, stream);

    // xom = x @ Om^T
    launch_dense_gemm(dout, xcur, din, OmT, nullptr, nullptr, 0, xom, N, stream);
    // bt = A^T xom (fp16) ; z_a = relu(bt)   (== fixed-point iteration 1 of 15)
    launch_spmm_bt(dout, cstart, csc_row, csc_val, xom, btb, z_a, N, stream);
    // remaining 14 iterations; ends in z_a (14 is even)
    for (int s = 0; s < 14; ++s) {
      const __half* zin = (s & 1) ? z_b : z_a;
      __half* zout = (s & 1) ? z_a : z_b;
      launch_fp_step(dout, cstart, csc_row, csc_val, zin, WpT, btb, zout, N, stream);
    }
    // x = z + x @ Pw^T + Pb ; elu for layers 0..3; layer 4 -> d_out
    float* outp = (i < 4) ? xnext : (float*)d_out;
    launch_dense_gemm(dout, xcur, din, PwT, Pb, z_a, (i < 4) ? 1 : 0, outp, N, stream);
    float* t = xcur; xcur = xnext; xnext = t;
  }
}

// Round 9
// 4798.861 us; speedup vs baseline: 2.3993x; 2.3993x over previous
//
#include <hip/hip_runtime.h>
#include <hip/hip_fp16.h>
#include <math.h>

#define THREADS 256

static inline int ceil_div(int a, int b) { return (a + b - 1) / b; }

__device__ __forceinline__ float wave_sum_all(float v) {
#pragma unroll
  for (int m = 1; m < 64; m <<= 1) v += __shfl_xor(v, m);
  return v;
}
__device__ __forceinline__ float wave_max_all(float v) {
#pragma unroll
  for (int m = 1; m < 64; m <<= 1) v = fmaxf(v, __shfl_xor(v, m));
  return v;
}

// 8-wide predicated fp16 sparse gather (R6-validated: VGPR 32, no spill):
// returns (sum_e val[e]*Z[row[e]*D+jj2], sum_e val[e]*Z[row[e]*D+jj2+1])
// 8 independent half2 loads in flight; f32 accumulate.
template <int D>
__device__ __forceinline__ float2 gather_row2h(const int* __restrict__ crow,
                                               const float* __restrict__ cval,
                                               const __half* __restrict__ Z, int e0, int e1,
                                               int jj2) {
  float2 acc[8];
#pragma unroll
  for (int u = 0; u < 8; ++u) acc[u] = make_float2(0.f, 0.f);
  for (int e = e0; e < e1; e += 8) {
    int r[8];
    float v[8];
#pragma unroll
    for (int u = 0; u < 8; ++u) {
      int ee = e + u;
      bool ok = ee < e1;
      r[u] = ok ? crow[ee] : 0;
      v[u] = ok ? cval[ee] : 0.f;
    }
    __half2 z[8];
#pragma unroll
    for (int u = 0; u < 8; ++u) z[u] = *(const __half2*)&Z[(size_t)r[u] * D + jj2];
#pragma unroll
    for (int u = 0; u < 8; ++u) {
      float2 f = __half22float2(z[u]);
      acc[u].x += v[u] * f.x;
      acc[u].y += v[u] * f.y;
    }
  }
  float2 s01 = make_float2(acc[0].x + acc[1].x, acc[0].y + acc[1].y);
  float2 s23 = make_float2(acc[2].x + acc[3].x, acc[2].y + acc[3].y);
  float2 s45 = make_float2(acc[4].x + acc[5].x, acc[4].y + acc[5].y);
  float2 s67 = make_float2(acc[6].x + acc[7].x, acc[6].y + acc[7].y);
  return make_float2((s01.x + s23.x) + (s45.x + s67.x), (s01.y + s23.y) + (s45.y + s67.y));
}

// ---------------- build helpers ----------------

__global__ __launch_bounds__(THREADS) void zero_i32(int* p, int n) {
  int i = blockIdx.x * THREADS + threadIdx.x;
  if (i < n) p[i] = 0;
}

__global__ __launch_bounds__(THREADS) void init_power(float* v, float* norm2, int n, float c) {
  int i = blockIdx.x * THREADS + threadIdx.x;
  if (i < n) v[i] = c;
  if (blockIdx.x == 0 && threadIdx.x < 64) norm2[threadIdx.x] = 0.f;
}

__global__ __launch_bounds__(THREADS) void hist_deg(const int* __restrict__ row,
                                                    const int* __restrict__ col,
                                                    int* rdeg, int* cdeg, int E) {
  int e = blockIdx.x * THREADS + threadIdx.x;
  if (e < E) {
    atomicAdd(&rdeg[row[e]], 1);
    atomicAdd(&cdeg[col[e]], 1);
  }
}

__global__ __launch_bounds__(THREADS) void scan1(const int* __restrict__ in, int* bsum, int L) {
  __shared__ int lds[THREADS];
  int idx = blockIdx.x * THREADS + threadIdx.x;
  lds[threadIdx.x] = (idx < L) ? in[idx] : 0;
  __syncthreads();
  for (int off = THREADS / 2; off > 0; off >>= 1) {
    if (threadIdx.x < off) lds[threadIdx.x] += lds[threadIdx.x + off];
    __syncthreads();
  }
  if (threadIdx.x == 0) bsum[blockIdx.x] = lds[0];
}

__global__ __launch_bounds__(THREADS) void scan2(int* bsum, int B) {
  __shared__ int lds[THREADS];
  int t = threadIdx.x;
  lds[t] = (t < B) ? bsum[t] : 0;
  __syncthreads();
  for (int off = 1; off < THREADS; off <<= 1) {
    int add = (t >= off) ? lds[t - off] : 0;
    __syncthreads();
    lds[t] += add;
    __syncthreads();
  }
  if (t < B) bsum[t] = (t == 0) ? 0 : lds[t - 1];
}

__global__ __launch_bounds__(THREADS) void scan3(int* data, const int* __restrict__ bsum, int L) {
  __shared__ int lds[THREADS];
  int t = threadIdx.x;
  int idx = blockIdx.x * THREADS + t;
  int v = (idx < L) ? data[idx] : 0;
  lds[t] = v;
  __syncthreads();
  for (int off = 1; off < THREADS; off <<= 1) {
    int add = (t >= off) ? lds[t - off] : 0;
    __syncthreads();
    lds[t] += add;
    __syncthreads();
  }
  if (idx < L) data[idx] = lds[t] - v + bsum[blockIdx.x];
}

__global__ __launch_bounds__(THREADS) void scatter_edges(
    const int* __restrict__ row, const int* __restrict__ col, const float* __restrict__ val,
    const int* __restrict__ rstart, int* rcur, int* csr_col, float* csr_val,
    const int* __restrict__ cstart, int* ccur, int* csc_row, float* csc_val, int E) {
  int e = blockIdx.x * THREADS + threadIdx.x;
  if (e < E) {
    int r = row[e], c = col[e];
    float v = val[e];
    int p = rstart[r] + atomicAdd(&rcur[r], 1);
    csr_col[p] = c;
    csr_val[p] = v;
    int q = cstart[c] + atomicAdd(&ccur[c], 1);
    csc_row[q] = r;
    csc_val[q] = v;
  }
}

// ---------------- power iteration (UNNORMALIZED chain) ----------------
__global__ __launch_bounds__(THREADS) void power_spmv_nn(
    const int* __restrict__ rs, const int* __restrict__ rcol, const float* __restrict__ rval,
    const float* __restrict__ vin, float* __restrict__ vout, int n) {
  int gid = blockIdx.x * THREADS + threadIdx.x;
  int node = gid >> 2;
  int sl = gid & 3;
  if (node >= n) return;
  int e0 = rs[node], e1 = rs[node + 1];
  float a0 = 0.f, a1 = 0.f, a2 = 0.f, a3 = 0.f;
  for (int e = e0 + sl; e < e1; e += 16) {
    int ee1 = e + 4, ee2 = e + 8, ee3 = e + 12;
    bool k1 = ee1 < e1, k2 = ee2 < e1, k3 = ee3 < e1;
    int r0 = rcol[e];
    int r1 = k1 ? rcol[ee1] : 0;
    int r2 = k2 ? rcol[ee2] : 0;
    int r3 = k3 ? rcol[ee3] : 0;
    float v0 = rval[e];
    float v1 = k1 ? rval[ee1] : 0.f;
    float v2 = k2 ? rval[ee2] : 0.f;
    float v3 = k3 ? rval[ee3] : 0.f;
    a0 += v0 * vin[r0];
    a1 += v1 * vin[r1];
    a2 += v2 * vin[r2];
    a3 += v3 * vin[r3];
  }
  float w = (a0 + a1) + (a2 + a3);
  w += __shfl_xor(w, 1);
  w += __shfl_xor(w, 2);
  if (sl == 0) vout[node] = w;
}

// n2[0] += ||u||^2 ; n2[1] += ||w||^2
__global__ __launch_bounds__(THREADS) void norm2_pair(const float* __restrict__ u,
                                                      const float* __restrict__ w,
                                                      float* norm2, int n) {
  int i = blockIdx.x * THREADS + threadIdx.x;
  float a = (i < n) ? u[i] : 0.f;
  float b = (i < n) ? w[i] : 0.f;
  float sa = wave_sum_all(a * a);
  float sb = wave_sum_all(b * b);
  __shared__ float pa[4], pb[4];
  if ((threadIdx.x & 63) == 0) {
    pa[threadIdx.x >> 6] = sa;
    pb[threadIdx.x >> 6] = sb;
  }
  __syncthreads();
  if (threadIdx.x == 0) atomicAdd(&norm2[0], pa[0] + pa[1] + pa[2] + pa[3]);
  if (threadIdx.x == 64) atomicAdd(&norm2[1], pb[0] + pb[1] + pb[2] + pb[3]);
}

// ---------------- transposes ----------------

__global__ __launch_bounds__(256) void transpose_feat(const float* __restrict__ in,
                                                      float* __restrict__ out, int n) {
  __shared__ float tile[32][33];
  int bx = blockIdx.x;
  int by = blockIdx.y;
  int x = bx * 32 + threadIdx.x;
  for (int dy = threadIdx.y; dy < 32; dy += 8) {
    int y = by * 32 + dy;
    tile[dy][threadIdx.x] = (x < n) ? in[(size_t)y * n + x] : 0.f;
  }
  __syncthreads();
  for (int dy = threadIdx.y; dy < 32; dy += 8) {
    int node = bx * 32 + dy;
    int feat = by * 32 + threadIdx.x;
    if (node < n) out[(size_t)node * 128 + feat] = tile[threadIdx.x][dy];
  }
}

__global__ __launch_bounds__(THREADS) void transpose_small(const float* __restrict__ in,
                                                           float* __restrict__ out, int rows,
                                                           int cols) {
  int idx = blockIdx.x * THREADS + threadIdx.x;
  if (idx < rows * cols) {
    int r = idx / cols, c = idx % cols;
    out[c * rows + r] = in[idx];
  }
}

// ---------------- projection (row-wise L1 projection via bisection) ----------------
template <int D>
__global__ __launch_bounds__(64) void project_row(const float* __restrict__ W,
                                                  float* __restrict__ WpT,
                                                  const float* __restrict__ norm2) {
  int o = blockIdx.x;
  int l = threadIdx.x;
  float rho = sqrtf(norm2[0] / norm2[1]) + 1e-12f;
  float k = 0.9f / rho;
  float a0 = (l < D) ? W[o * D + l] : 0.f;
  float a1 = (64 + l < D) ? W[o * D + 64 + l] : 0.f;
  float ab0 = fabsf(a0), ab1 = fabsf(a1);
  float s = wave_sum_all(ab0 + ab1);
  float mx = wave_max_all(fmaxf(ab0, ab1));
  float w0 = a0, w1 = a1;
  if (s > k) {
    float lo = 0.f, hi = mx;
    for (int it = 0; it < 50; ++it) {
      float mid = 0.5f * (lo + hi);
      float g = wave_sum_all(fmaxf(ab0 - mid, 0.f) + fmaxf(ab1 - mid, 0.f));
      if (g > k) lo = mid; else hi = mid;
    }
    float theta = 0.5f * (lo + hi);
    w0 = copysignf(fmaxf(ab0 - theta, 0.f), a0);
    w1 = copysignf(fmaxf(ab1 - theta, 0.f), a1);
  }
  if (l < D) WpT[l * D + o] = w0;
  if (64 + l < D) WpT[(64 + l) * D + o] = w1;
}

// ---------------- spmm for bt (fp16 in, fp16 out) + Zinit = relu(bt) ----------------
template <int DOUT>
__global__ __launch_bounds__(THREADS, 8) void spmm_bt(
    const int* __restrict__ cstart, const int* __restrict__ crow, const float* __restrict__ cval,
    const __half* __restrict__ X, __half* __restrict__ bt, __half* __restrict__ Zinit, int n) {
  constexpr int HD = DOUT / 2;
  int idx = blockIdx.x * THREADS + threadIdx.x;
  int node = idx / HD;
  int jj2 = (idx % HD) * 2;
  if (node >= n) return;
  int e0 = cstart[node], e1 = cstart[node + 1];
  float2 acc = gather_row2h<DOUT>(crow, cval, X, e0, e1, jj2);
  size_t o = (size_t)node * DOUT + jj2;
  *(__half2*)&bt[o] = __floats2half2_rn(acc.x, acc.y);
  *(__half2*)&Zinit[o] = __floats2half2_rn(fmaxf(acc.x, 0.f), fmaxf(acc.y, 0.f));
}

// ---------------- fused fixed-point step: Zout = relu( (A^T Zin) @ WpT + bt ) ------
// Zin/Zout/bt fp16; WpT, LDS tile, accumulation f32. R6-validated structure.
template <int DOUT, int NB>
__global__ __launch_bounds__(THREADS, 8) void fp_step(
    const int* __restrict__ cstart, const int* __restrict__ crow, const float* __restrict__ cval,
    const __half* __restrict__ Zin, const float* __restrict__ WpT, const __half* __restrict__ bt,
    __half* __restrict__ Zout, int n) {
  constexpr int TO = DOUT / 4;
  constexpr int TN = THREADS / TO;
  constexpr int NT = NB / TN;
  static_assert(NT >= 1, "NB too small");
  __shared__ float sT[NB][DOUT + 2];
  const int node0 = blockIdx.x * NB;
  const int tid = threadIdx.x;
  // phase 1: gather S rows into LDS (row-major, float2 writes)
  {
    constexpr int HD = DOUT / 2;
    constexpr int LG = THREADS / HD;
    const int jj2 = (tid % HD) * 2;
    const int lg = tid / HD;
    for (int nn = lg; nn < NB; nn += LG) {
      int node = node0 + nn;
      float2 acc = make_float2(0.f, 0.f);
      if (node < n) {
        int e0 = cstart[node], e1 = cstart[node + 1];
        acc = gather_row2h<DOUT>(crow, cval, Zin, e0, e1, jj2);
      }
      *(float2*)&sT[nn][jj2] = acc;
    }
  }
  __syncthreads();
  // phase 2: register-tiled GEMM  C[n][o] = sum_j S[n][j] * WpT[j][o]
  const int o4 = tid % TO, tg = tid / TO;
  const int o0 = o4 * 4;
  float acc[NT][4];
#pragma unroll
  for (int a = 0; a < NT; ++a) acc[a][0] = acc[a][1] = acc[a][2] = acc[a][3] = 0.f;
  for (int jz = 0; jz < DOUT; ++jz) {
    const float4 w4 = *(const float4*)&WpT[jz * DOUT + o0];
#pragma unroll
    for (int a = 0; a < NT; ++a) {
      float sv = sT[tg * NT + a][jz];
      acc[a][0] += sv * w4.x;
      acc[a][1] += sv * w4.y;
      acc[a][2] += sv * w4.z;
      acc[a][3] += sv * w4.w;
    }
  }
#pragma unroll
  for (int a = 0; a < NT; ++a) {
    int node = node0 + tg * NT + a;
    if (node < n) {
      size_t o = (size_t)node * DOUT + o0;
      float2 b01 = __half22float2(*(const __half2*)&bt[o]);
      float2 b23 = __half22float2(*(const __half2*)&bt[o + 2]);
      float zx = fmaxf(acc[a][0] + b01.x, 0.f);
      float zy = fmaxf(acc[a][1] + b01.y, 0.f);
      float zz = fmaxf(acc[a][2] + b23.x, 0.f);
      float zw = fmaxf(acc[a][3] + b23.y, 0.f);
      *(__half2*)&Zout[o] = __floats2half2_rn(zx, zy);
      *(__half2*)&Zout[o + 2] = __floats2half2_rn(zz, zw);
    }
  }
}

// ---------------- dense GEMM: Out = act( X @ MT + bias + Addh ) ----------------
// OUTH selects fp16 output (for xom) vs f32 output (for layer residual / d_out).
template <int DOUT, int NB, bool OUTH>
__global__ __launch_bounds__(THREADS) void dense_gemm(
    const float* __restrict__ X, int din, const float* __restrict__ MT,
    const float* __restrict__ bias, const __half* __restrict__ Addh, int act,
    void* __restrict__ OutV, int n) {
  constexpr int TO = DOUT / 4;
  constexpr int TN = THREADS / TO;
  constexpr int NT = NB / TN;
  __shared__ float xs[NB][129];
  const int node0 = blockIdx.x * NB;
  const int tid = threadIdx.x;
  for (int idx = tid; idx < NB * din; idx += THREADS) {
    int nn = idx / din, j = idx % din;
    int node = node0 + nn;
    xs[nn][j] = (node < n) ? X[(size_t)node * din + j] : 0.f;
  }
  __syncthreads();
  const int o4 = tid % TO, tg = tid / TO;
  const int o0 = o4 * 4;
  float acc[NT][4];
#pragma unroll
  for (int a = 0; a < NT; ++a) acc[a][0] = acc[a][1] = acc[a][2] = acc[a][3] = 0.f;
  for (int j = 0; j < din; ++j) {
    const float4 m4 = *(const float4*)&MT[j * DOUT + o0];
#pragma unroll
    for (int a = 0; a < NT; ++a) {
      float sv = xs[tg * NT + a][j];
      acc[a][0] += sv * m4.x;
      acc[a][1] += sv * m4.y;
      acc[a][2] += sv * m4.z;
      acc[a][3] += sv * m4.w;
    }
  }
#pragma unroll
  for (int a = 0; a < NT; ++a) {
    int node = node0 + tg * NT + a;
    if (node < n) {
      float4 r;
      r.x = acc[a][0]; r.y = acc[a][1]; r.z = acc[a][2]; r.w = acc[a][3];
      if (bias) {
        r.x += bias[o0]; r.y += bias[o0 + 1]; r.z += bias[o0 + 2]; r.w += bias[o0 + 3];
      }
      if (Addh) {
        size_t o = (size_t)node * DOUT + o0;
        float2 a01 = __half22float2(*(const __half2*)&Addh[o]);
        float2 a23 = __half22float2(*(const __half2*)&Addh[o + 2]);
        r.x += a01.x; r.y += a01.y; r.z += a23.x; r.w += a23.y;
      }
      if (act == 1) {
        r.x = (r.x > 0.f) ? r.x : expm1f(r.x);
        r.y = (r.y > 0.f) ? r.y : expm1f(r.y);
        r.z = (r.z > 0.f) ? r.z : expm1f(r.z);
        r.w = (r.w > 0.f) ? r.w : expm1f(r.w);
      }
      size_t o = (size_t)node * DOUT + o0;
      if (OUTH) {
        __half* O = (__half*)OutV;
        *(__half2*)&O[o] = __floats2half2_rn(r.x, r.y);
        *(__half2*)&O[o + 2] = __floats2half2_rn(r.z, r.w);
      } else {
        float* O = (float*)OutV;
        *(float4*)&O[o] = r;
      }
    }
  }
}

// ---------------- host-side dispatch ----------------

static void launch_project(int dout, const float* W, float* WpT, const float* norm2,
                           hipStream_t s) {
  switch (dout) {
    case 128: project_row<128><<<128, 64, 0, s>>>(W, WpT, norm2); break;
    case 64: project_row<64><<<64, 64, 0, s>>>(W, WpT, norm2); break;
    case 32: project_row<32><<<32, 64, 0, s>>>(W, WpT, norm2); break;
    case 16: project_row<16><<<16, 64, 0, s>>>(W, WpT, norm2); break;
  }
}

static void launch_spmm_bt(int dout, const int* cs, const int* cr, const float* cv,
                           const __half* X, __half* bt, __half* Zi, int n, hipStream_t s) {
  int g = ceil_div(n * dout / 2, THREADS);
  switch (dout) {
    case 128: spmm_bt<128><<<g, THREADS, 0, s>>>(cs, cr, cv, X, bt, Zi, n); break;
    case 64: spmm_bt<64><<<g, THREADS, 0, s>>>(cs, cr, cv, X, bt, Zi, n); break;
    case 32: spmm_bt<32><<<g, THREADS, 0, s>>>(cs, cr, cv, X, bt, Zi, n); break;
    case 16: spmm_bt<16><<<g, THREADS, 0, s>>>(cs, cr, cv, X, bt, Zi, n); break;
  }
}

static void launch_fp_step(int dout, const int* cs, const int* cr, const float* cv,
                           const __half* Zin, const float* WpT, const __half* bt, __half* Zout,
                           int n, hipStream_t s) {
  switch (dout) {
    case 128: fp_step<128, 16><<<ceil_div(n, 16), THREADS, 0, s>>>(cs, cr, cv, Zin, WpT, bt, Zout, n); break;
    case 64: fp_step<64, 16><<<ceil_div(n, 16), THREADS, 0, s>>>(cs, cr, cv, Zin, WpT, bt, Zout, n); break;
    case 32: fp_step<32, 32><<<ceil_div(n, 32), THREADS, 0, s>>>(cs, cr, cv, Zin, WpT, bt, Zout, n); break;
    case 16: fp_step<16, 64><<<ceil_div(n, 64), THREADS, 0, s>>>(cs, cr, cv, Zin, WpT, bt, Zout, n); break;
  }
}

static void launch_dense_gemm_h(int dout, const float* X, int din, const float* MT,
                                __half* Out, int n, hipStream_t s) {
  switch (dout) {
    case 128: dense_gemm<128, 32, true><<<ceil_div(n, 32), THREADS, 0, s>>>(X, din, MT, nullptr, nullptr, 0, Out, n); break;
    case 64: dense_gemm<64, 32, true><<<ceil_div(n, 32), THREADS, 0, s>>>(X, din, MT, nullptr, nullptr, 0, Out, n); break;
    case 32: dense_gemm<32, 32, true><<<ceil_div(n, 32), THREADS, 0, s>>>(X, din, MT, nullptr, nullptr, 0, Out, n); break;
    case 16: dense_gemm<16, 64, true><<<ceil_div(n, 64), THREADS, 0, s>>>(X, din, MT, nullptr, nullptr, 0, Out, n); break;
  }
}

static void launch_dense_gemm_f(int dout, const float* X, int din, const float* MT,
                                const float* bias, const __half* Addh, int act, float* Out,
                                int n, hipStream_t s) {
  switch (dout) {
    case 128: dense_gemm<128, 32, false><<<ceil_div(n, 32), THREADS, 0, s>>>(X, din, MT, bias, Addh, act, Out, n); break;
    case 64: dense_gemm<64, 32, false><<<ceil_div(n, 32), THREADS, 0, s>>>(X, din, MT, bias, Addh, act, Out, n); break;
    case 32: dense_gemm<32, 32, false><<<ceil_div(n, 32), THREADS, 0, s>>>(X, din, MT, bias, Addh, act, Out, n); break;
    case 16: dense_gemm<16, 64, false><<<ceil_div(n, 64), THREADS, 0, s>>>(X, din, MT, bias, Addh, act, Out, n); break;
  }
}

extern "C" void kernel_launch(void* const* d_in, const int* in_sizes, int n_in, void* d_out,
                              int out_size, void* d_ws, size_t ws_size, hipStream_t stream) {
  const float* features = (const float*)d_in[0];
  const int* row = (const int*)d_in[1];
  const int* col = (const int*)d_in[2];
  const float* val = (const float*)d_in[3];
  const int N = in_sizes[0] / 128;
  const int E = in_sizes[1];
  static const int DIN[5] = {128, 128, 64, 64, 32};
  static const int DOUT[5] = {128, 64, 64, 32, 16};

  char* base = (char*)d_ws;
  size_t off = 0;
  auto alloc = [&](size_t bytes) -> void* {
    off = (off + 255) & ~(size_t)255;
    void* p = (void*)(base + off);
    off += bytes;
    return p;
  };

  int* rstart = (int*)alloc((size_t)(N + 1) * 4);
  int* cstart = (int*)alloc((size_t)(N + 1) * 4);
  int* rcur = (int*)alloc((size_t)N * 4);
  int* ccur = (int*)alloc((size_t)N * 4);
  int* bsum = (int*)alloc(256 * 4);
  float* norm2 = (float*)alloc(64 * 4);
  float* v_a = (float*)alloc((size_t)N * 4);
  float* v_b = (float*)alloc((size_t)N * 4);
  int* csr_col = (int*)alloc((size_t)E * 4);
  float* csr_val = (float*)alloc((size_t)E * 4);
  int* csc_row = (int*)alloc((size_t)E * 4);
  float* csc_val = (float*)alloc((size_t)E * 4);
  float* WpT = (float*)alloc(16384 * 4);
  float* OmT = (float*)alloc(16384 * 4);
  float* PwT = (float*)alloc(16384 * 4);
  float* x0 = (float*)alloc((size_t)N * 128 * 4);
  float* x1 = (float*)alloc((size_t)N * 128 * 4);
  __half* xom = (__half*)alloc((size_t)N * 128 * 2);
  __half* btb = (__half*)alloc((size_t)N * 128 * 2);
  __half* z_a = (__half*)alloc((size_t)N * 128 * 2);
  __half* z_b = (__half*)alloc((size_t)N * 128 * 2);

  const int gN = ceil_div(N, THREADS);
  const int gE = ceil_div(E, THREADS);
  const int L = N + 1;
  const int B = ceil_div(L, THREADS);

  // ---- build CSR/CSC ----
  zero_i32<<<ceil_div(N + 1, THREADS), THREADS, 0, stream>>>(rstart, N + 1);
  zero_i32<<<ceil_div(N + 1, THREADS), THREADS, 0, stream>>>(cstart, N + 1);
  zero_i32<<<gN, THREADS, 0, stream>>>(rcur, N);
  zero_i32<<<gN, THREADS, 0, stream>>>(ccur, N);
  init_power<<<gN, THREADS, 0, stream>>>(v_a, norm2, N, (float)(1.0 / sqrt((double)N)));
  hist_deg<<<gE, THREADS, 0, stream>>>(row, col, rstart, cstart, E);
  scan1<<<B, THREADS, 0, stream>>>(rstart, bsum, L);
  scan2<<<1, THREADS, 0, stream>>>(bsum, B);
  scan3<<<B, THREADS, 0, stream>>>(rstart, bsum, L);
  scan1<<<B, THREADS, 0, stream>>>(cstart, bsum, L);
  scan2<<<1, THREADS, 0, stream>>>(bsum, B);
  scan3<<<B, THREADS, 0, stream>>>(cstart, bsum, L);
  scatter_edges<<<gE, THREADS, 0, stream>>>(row, col, val, rstart, rcur, csr_col, csr_val,
                                            cstart, ccur, csc_row, csc_val, E);

  // ---- x = features^T ----
  {
    dim3 grid(ceil_div(N, 32), 4);
    dim3 block(32, 8);
    transpose_feat<<<grid, block, 0, stream>>>(features, x0, N);
  }

  // ---- spectral radius: 51 unnormalized SpMVs, then one ratio-norm ----
  {
    int g4 = ceil_div(N * 4, THREADS);
    for (int k = 1; k <= 51; ++k) {
      const float* vin = (k & 1) ? v_a : v_b;
      float* vout = (k & 1) ? v_b : v_a;
      power_spmv_nn<<<g4, THREADS, 0, stream>>>(rstart, csr_col, csr_val, vin, vout, N);
    }
    // v50 ended in v_a, v51 in v_b
    norm2_pair<<<gN, THREADS, 0, stream>>>(v_b, v_a, norm2, N);
  }

  // ---- layers ----
  float* xcur = x0;
  float* xnext = x1;
  for (int i = 0; i < 5; ++i) {
    const int din = DIN[i], dout = DOUT[i];
    const float* W = (const float*)d_in[4 + 4 * i];
    const float* Om = (const float*)d_in[5 + 4 * i];
    const float* Pw = (const float*)d_in[6 + 4 * i];
    const float* Pb = (const float*)d_in[7 + 4 * i];

    transpose_small<<<ceil_div(dout * din, THREADS), THREADS, 0, stream>>>(Om, OmT, dout, din);
    transpose_small<<<ceil_div(dout * din, THREADS), THREADS, 0, stream>>>(Pw, PwT, dout, din);
    launch_project(dout, W, WpT, norm2, stream);

    // xom = x @ Om^T   (fp16 output to halve spmm_bt gather bytes)
    launch_dense_gemm_h(dout, xcur, din, OmT, xom, N, stream);
    // bt = A^T xom (fp16) ; z_a = relu(bt)   (== fixed-point iteration 1 of 15)
    launch_spmm_bt(dout, cstart, csc_row, csc_val, xom, btb, z_a, N, stream);
    // remaining 14 iterations; ends in z_a (14 is even)
    for (int s = 0; s < 14; ++s) {
      const __half* zin = (s & 1) ? z_b : z_a;
      __half* zout = (s & 1) ? z_a : z_b;
      launch_fp_step(dout, cstart, csc_row, csc_val, zin, WpT, btb, zout, N, stream);
    }
    // x = z + x @ Pw^T + Pb ; elu for layers 0..3; layer 4 -> d_out
    float* outp = (i < 4) ? xnext : (float*)d_out;
    launch_dense_gemm_f(dout, xcur, din, PwT, Pb, z_a, (i < 4) ? 1 : 0, outp, N, stream);
    float* t = xcur; xcur = xnext; xnext = t;
  }
}